// Round 6
// baseline (442.382 us; speedup 1.0000x reference)
//
#include <hip/hip_runtime.h>
#include <math.h>

#define SEQ 2048
#define DIM 1024
#define NH 16

typedef short s8v __attribute__((ext_vector_type(8)));
typedef float f4v __attribute__((ext_vector_type(4)));
typedef unsigned int u2v __attribute__((ext_vector_type(2)));

__device__ __forceinline__ unsigned short f2bf(float x) {   // RNE
    unsigned u = __float_as_uint(x);
    u += 0x7FFFu + ((u >> 16) & 1u);
    return (unsigned short)(u >> 16);
}
// pack bf16(a),bf16(b) (round-half-up, a in low16) via v_perm_b32
__device__ __forceinline__ unsigned pk_bf16(float a, float b) {
    unsigned ua = __float_as_uint(a) + 0x8000u;
    unsigned ub = __float_as_uint(b) + 0x8000u;
    return __builtin_amdgcn_perm(ub, ua, 0x07060302);
}

// ---------------- q,k,v fp32 -> bf16 (one launch) ----------------
__global__ void conv3_f32_bf16(const float* __restrict__ q, const float* __restrict__ k,
                               const float* __restrict__ v,
                               unsigned short* __restrict__ qb, unsigned short* __restrict__ kb,
                               unsigned short* __restrict__ vb, int n4) {
    const float* in = (blockIdx.y == 0) ? q : (blockIdx.y == 1) ? k : v;
    unsigned short* out = (blockIdx.y == 0) ? qb : (blockIdx.y == 1) ? kb : vb;
    int i = blockIdx.x * 256 + threadIdx.x;
    if (i >= n4) return;
    float4 x = ((const float4*)in)[i];
    ushort4 o;
    o.x = f2bf(x.x); o.y = f2bf(x.y); o.z = f2bf(x.z); o.w = f2bf(x.w);
    ((ushort4*)out)[i] = o;
}

// ---------------- 4x W[K,N] fp32 -> WT[N,K] bf16 (one launch) ----------------
__global__ __launch_bounds__(256)
void convT4_f32_bf16(const float* __restrict__ W0, const float* __restrict__ W1,
                     const float* __restrict__ W2, const float* __restrict__ W3,
                     unsigned short* __restrict__ T0, unsigned short* __restrict__ T1,
                     unsigned short* __restrict__ T2, unsigned short* __restrict__ T3) {
    const float* W = (blockIdx.z == 0) ? W0 : (blockIdx.z == 1) ? W1 : (blockIdx.z == 2) ? W2 : W3;
    unsigned short* WT = (blockIdx.z == 0) ? T0 : (blockIdx.z == 1) ? T1 : (blockIdx.z == 2) ? T2 : T3;
    __shared__ float T[64][65];
    const int t = threadIdx.x;
    const int n0 = blockIdx.x * 64, k0 = blockIdx.y * 64;
    #pragma unroll
    for (int i = 0; i < 4; i++) {
        int idx = t + i * 256;
        int r = idx >> 4, c4 = idx & 15;
        float4 v = *(const float4*)&W[(size_t)(k0 + r) * DIM + n0 + c4 * 4];
        T[r][c4 * 4 + 0] = v.x; T[r][c4 * 4 + 1] = v.y;
        T[r][c4 * 4 + 2] = v.z; T[r][c4 * 4 + 3] = v.w;
    }
    __syncthreads();
    #pragma unroll
    for (int i = 0; i < 4; i++) {
        int idx = t + i * 256;
        int rn = idx >> 4, c4 = idx & 15;
        ushort4 o;
        o.x = f2bf(T[c4 * 4 + 0][rn]);
        o.y = f2bf(T[c4 * 4 + 1][rn]);
        o.z = f2bf(T[c4 * 4 + 2][rn]);
        o.w = f2bf(T[c4 * 4 + 3][rn]);
        *(ushort4*)&WT[(size_t)(n0 + rn) * DIM + k0 + c4 * 4] = o;
    }
}

// ---------------- GEMM core (m97 staging) ----------
// C = A[M,K]*BT[N,K]^T + bias. 128x128 tile, BK=64, global_load_lds staging.
// MODE 0: fp32 out [M,DIM].
// MODE 1: bf16 head-split [B,NH,SEQ,64] * scale.
// MODE 3: bf16 TRANSPOSED head-split [B*NH, 64(d), SEQ]  (for V: feeds attn Vs directly)
template<int MODE>
__device__ __forceinline__
void gemm_core(const unsigned short* __restrict__ A,
               const unsigned short* __restrict__ BT,
               const float* __restrict__ bias, void* __restrict__ outp,
               float scale, int bx, int by)
{
    __shared__ __align__(16) unsigned short As[128 * 64];
    __shared__ __align__(16) unsigned short Bs[128 * 64];
    const int t = threadIdx.x;
    const int lane = t & 63, w = t >> 6;
    const int l15 = lane & 15, quad = lane >> 4;
    const int bm = by * 128, bn = bx * 128;
    const int wm = (w & 1) * 64, wn = (w >> 1) * 64;
    const int lrow = lane >> 3, lcol = (lane & 7) * 8;

    f4v acc[4][4];
    #pragma unroll
    for (int mi = 0; mi < 4; mi++)
        #pragma unroll
        for (int ni = 0; ni < 4; ni++)
            acc[mi][ni] = (f4v){0.f, 0.f, 0.f, 0.f};

    for (int k0 = 0; k0 < DIM; k0 += 64) {
        __syncthreads();
        #pragma unroll
        for (int i = 0; i < 4; i++) {
            int ci = w + i * 4;
            int row = ci * 8 + lrow;
            __builtin_amdgcn_global_load_lds(
                (const __attribute__((address_space(1))) unsigned int*)
                    (A + (size_t)(bm + row) * DIM + k0 + lcol),
                (__attribute__((address_space(3))) unsigned int*)(As + ci * 8 * 64),
                16, 0, 0);
            __builtin_amdgcn_global_load_lds(
                (const __attribute__((address_space(1))) unsigned int*)
                    (BT + (size_t)(bn + row) * DIM + k0 + lcol),
                (__attribute__((address_space(3))) unsigned int*)(Bs + ci * 8 * 64),
                16, 0, 0);
        }
        __syncthreads();
        #pragma unroll
        for (int kc = 0; kc < 2; kc++) {
            const int ko = kc * 32 + quad * 8;
            s8v af[4], bf[4];
            #pragma unroll
            for (int mi = 0; mi < 4; mi++)
                af[mi] = *(const s8v*)&As[(wm + mi * 16 + l15) * 64 + ko];
            #pragma unroll
            for (int ni = 0; ni < 4; ni++)
                bf[ni] = *(const s8v*)&Bs[(wn + ni * 16 + l15) * 64 + ko];
            #pragma unroll
            for (int mi = 0; mi < 4; mi++)
                #pragma unroll
                for (int ni = 0; ni < 4; ni++)
                    acc[mi][ni] = __builtin_amdgcn_mfma_f32_16x16x32_bf16(
                        af[mi], bf[ni], acc[mi][ni], 0, 0, 0);
        }
    }

    if constexpr (MODE == 3) {
        // transpose the 128x128 tile through LDS, write [bh][d][s] coalesced
        __shared__ __align__(16) unsigned short T[128 * 132];
        #pragma unroll
        for (int mi = 0; mi < 4; mi++)
            #pragma unroll
            for (int ni = 0; ni < 4; ni++)
                #pragma unroll
                for (int r = 0; r < 4; r++) {
                    int ml = wm + mi * 16 + quad * 4 + r;
                    int nl = wn + ni * 16 + l15;
                    T[nl * 132 + ml] = f2bf(acc[mi][ni][r] + bias[bn + nl]);
                }
        __syncthreads();
        const int b = bm >> 11, s0 = bm & (SEQ - 1);
        unsigned short* outT = (unsigned short*)outp;
        #pragma unroll
        for (int i = 0; i < 8; i++) {
            int c = t + i * 256;
            int d = c >> 4, cc = c & 15;        // d: 0..127 within tile, cc: 16B chunk
            int n = bn + d;
            int h = n >> 6, dk = n & 63;
            s8v val = *(const s8v*)&T[d * 132 + cc * 8];
            *(s8v*)&outT[((size_t)((b * NH + h) * 64 + dk)) * SEQ + s0 + cc * 8] = val;
        }
    } else {
        #pragma unroll
        for (int mi = 0; mi < 4; mi++) {
            #pragma unroll
            for (int ni = 0; ni < 4; ni++) {
                #pragma unroll
                for (int r = 0; r < 4; r++) {
                    int m = bm + wm + mi * 16 + quad * 4 + r;
                    int n = bn + wn + ni * 16 + l15;
                    float val = acc[mi][ni][r] + bias[n];
                    if (MODE == 0) {
                        ((float*)outp)[(size_t)m * DIM + n] = val;
                    } else {
                        val *= scale;
                        int b = m >> 11, s = m & (SEQ - 1);
                        int h = n >> 6, dk = n & 63;
                        ((unsigned short*)outp)[(((size_t)(b * NH + h)) * SEQ + s) * 64 + dk] = f2bf(val);
                    }
                }
            }
        }
    }
}

// Q and K projections in one launch (z selects). Q scale folds 1/sqrt(64) * log2(e)
// so the attention softmax can use exp2 (exactly e-softmax, shift-free).
__global__ __launch_bounds__(256)
void qk_gemm(const unsigned short* __restrict__ qb, const unsigned short* __restrict__ kb,
             const unsigned short* __restrict__ WqT, const unsigned short* __restrict__ WkT,
             const float* __restrict__ bq, const float* __restrict__ bk,
             unsigned short* __restrict__ qp, unsigned short* __restrict__ kp)
{
    const int z = blockIdx.z;
    const unsigned short* A  = (z == 0) ? qb : kb;
    const unsigned short* BT = (z == 0) ? WqT : WkT;
    const float* bias        = (z == 0) ? bq : bk;
    unsigned short* outp     = (z == 0) ? qp : kp;
    float scale = (z == 0) ? 0.125f * 1.44269504f : 1.0f;
    gemm_core<1>(A, BT, bias, outp, scale, blockIdx.x, blockIdx.y);
}

// V projection with transposed output [bh][d][s]
__global__ __launch_bounds__(256)
void v_gemm(const unsigned short* __restrict__ vb, const unsigned short* __restrict__ WvT,
            const float* __restrict__ bv, unsigned short* __restrict__ vpT)
{
    gemm_core<3>(vb, WvT, bv, vpT, 1.0f, blockIdx.x, blockIdx.y);
}

__global__ __launch_bounds__(256)
void out_gemm(const unsigned short* __restrict__ A, const unsigned short* __restrict__ BT,
              const float* __restrict__ bias, float* __restrict__ outp)
{
    gemm_core<0>(A, BT, bias, outp, 1.0f, blockIdx.x, blockIdx.y);
}

// ---------------- MFMA flash attention v4 ----------------
// Q pre-scaled by log2e/8 -> p = exp2(s) (no-max softmax, shift-free).
// S^T trick (A=K, B=Q): C gives q=l15, key=quad*4+r+16mf -> b64 P stores.
// l-sums via MFMA with all-ones B frag (rows match o_acc layout; l consistent
// with the bf16 P used in PV). 32 q/wave, 128-q block, 64-key tiles x32.
__global__ __launch_bounds__(256)
void attn_mfma(const unsigned short* __restrict__ Q,
               const unsigned short* __restrict__ Kp,
               const unsigned short* __restrict__ VT,
               unsigned short* __restrict__ AO)
{
    __shared__ __align__(16) unsigned short Ks[64 * 72];     // [key][d]
    __shared__ __align__(16) unsigned short Vs[64 * 72];     // [d][key]
    __shared__ __align__(16) unsigned short Ps[4][32 * 72];  // per-wave P [q][key]
    const int t = threadIdx.x;
    const int lane = t & 63, w = t >> 6;
    const int l15 = lane & 15, quad = lane >> 4;
    const int bh = blockIdx.y, q0 = blockIdx.x * 128;

    const unsigned short* qbase = Q + ((size_t)bh * SEQ + q0 + w * 32) * 64;
    const unsigned short* vtbase = VT + (size_t)bh * 64 * SEQ;

    const int srow = t >> 3, scol = (t & 7) * 8;
    const unsigned short* kptr = Kp + (size_t)bh * SEQ * 64 + (size_t)srow * 64 + scol;
    const unsigned short* vtptr = vtbase + (size_t)srow * SEQ + scol;

    s8v qf[2][2];
    #pragma unroll
    for (int qs = 0; qs < 2; qs++)
        #pragma unroll
        for (int kc = 0; kc < 2; kc++)
            qf[qs][kc] = *(const s8v*)&qbase[(qs * 16 + l15) * 64 + kc * 32 + quad * 8];

    s8v ones;
    #pragma unroll
    for (int j = 0; j < 8; j++) ones[j] = (short)0x3F80;   // bf16 1.0

    f4v o_acc[2][4], l_acc[2];
    #pragma unroll
    for (int qs = 0; qs < 2; qs++) {
        l_acc[qs] = (f4v){0.f, 0.f, 0.f, 0.f};
        #pragma unroll
        for (int df = 0; df < 4; df++) o_acc[qs][df] = (f4v){0.f, 0.f, 0.f, 0.f};
    }

    unsigned short* Pw = (unsigned short*)Ps[w];
    const int klds0 = srow * 72 + scol, klds1 = (srow + 32) * 72 + scol;

    for (int kt = 0; kt < 32; kt++) {
        __syncthreads();   // prior-iteration frag reads done before restage
        *(s8v*)&Ks[klds0] = *(const s8v*)(kptr);
        *(s8v*)&Ks[klds1] = *(const s8v*)(kptr + 32 * 64);
        *(s8v*)&Vs[klds0] = *(const s8v*)(vtptr);
        *(s8v*)&Vs[klds1] = *(const s8v*)(vtptr + 32 * SEQ);
        kptr += 64 * 64; vtptr += 64;
        __syncthreads();

        // S^T = K*Q^T
        f4v s_acc[2][4];   // [qs][mf]: S^T[key=mf*16+quad*4+r][q=qs*16+l15]
        #pragma unroll
        for (int qs = 0; qs < 2; qs++)
            #pragma unroll
            for (int mf = 0; mf < 4; mf++) s_acc[qs][mf] = (f4v){0.f, 0.f, 0.f, 0.f};
        #pragma unroll
        for (int kc = 0; kc < 2; kc++) {
            const int ko = kc * 32 + quad * 8;
            #pragma unroll
            for (int mf = 0; mf < 4; mf++) {
                s8v kf = *(const s8v*)&Ks[(mf * 16 + l15) * 72 + ko];
                #pragma unroll
                for (int qs = 0; qs < 2; qs++)
                    s_acc[qs][mf] = __builtin_amdgcn_mfma_f32_16x16x32_bf16(
                        kf, qf[qs][kc], s_acc[qs][mf], 0, 0, 0);
            }
        }

        // p = exp2(s) (Q pre-scaled by log2e/8); packed bf16 stores
        #pragma unroll
        for (int qs = 0; qs < 2; qs++) {
            #pragma unroll
            for (int mf = 0; mf < 4; mf++) {
                float p0 = exp2f(s_acc[qs][mf][0]);
                float p1 = exp2f(s_acc[qs][mf][1]);
                float p2 = exp2f(s_acc[qs][mf][2]);
                float p3 = exp2f(s_acc[qs][mf][3]);
                u2v pk;
                pk[0] = pk_bf16(p0, p1);
                pk[1] = pk_bf16(p2, p3);
                *(u2v*)&Pw[(qs * 16 + l15) * 72 + mf * 16 + quad * 4] = pk;
            }
        }

        // O += P*V ; l += P*1  (same-wave LDS write->read is program-ordered)
        #pragma unroll
        for (int kc2 = 0; kc2 < 2; kc2++) {
            const int ko = kc2 * 32 + quad * 8;
            s8v pf0 = *(const s8v*)&Pw[(0 * 16 + l15) * 72 + ko];
            s8v pf1 = *(const s8v*)&Pw[(1 * 16 + l15) * 72 + ko];
            #pragma unroll
            for (int df = 0; df < 4; df++) {
                s8v vf = *(const s8v*)&Vs[(df * 16 + l15) * 72 + ko];
                o_acc[0][df] = __builtin_amdgcn_mfma_f32_16x16x32_bf16(pf0, vf, o_acc[0][df], 0, 0, 0);
                o_acc[1][df] = __builtin_amdgcn_mfma_f32_16x16x32_bf16(pf1, vf, o_acc[1][df], 0, 0, 0);
            }
            l_acc[0] = __builtin_amdgcn_mfma_f32_16x16x32_bf16(pf0, ones, l_acc[0], 0, 0, 0);
            l_acc[1] = __builtin_amdgcn_mfma_f32_16x16x32_bf16(pf1, ones, l_acc[1], 0, 0, 0);
        }
    }

    // l_acc rows (quad*4+r) match o_acc rows exactly — no cross-lane reduce needed
    const int b = bh >> 4, h = bh & (NH - 1);
    #pragma unroll
    for (int qs = 0; qs < 2; qs++) {
        #pragma unroll
        for (int r = 0; r < 4; r++) {
            int s = q0 + w * 32 + qs * 16 + quad * 4 + r;
            float linv = 1.0f / l_acc[qs][r];
            #pragma unroll
            for (int df = 0; df < 4; df++)
                AO[((size_t)(b * SEQ + s)) * DIM + h * 64 + df * 16 + l15] =
                    f2bf(o_acc[qs][df][r] * linv);
        }
    }
}

extern "C" void kernel_launch(void* const* d_in, const int* in_sizes, int n_in,
                              void* d_out, int out_size, void* d_ws, size_t ws_size,
                              hipStream_t stream) {
    const float* q  = (const float*)d_in[0];
    const float* k  = (const float*)d_in[1];
    const float* v  = (const float*)d_in[2];
    const float* Wq = (const float*)d_in[3];
    const float* bq = (const float*)d_in[4];
    const float* Wk = (const float*)d_in[5];
    const float* bk = (const float*)d_in[6];
    const float* Wv = (const float*)d_in[7];
    const float* bv = (const float*)d_in[8];
    const float* Wo = (const float*)d_in[9];
    const float* bo = (const float*)d_in[10];
    float* out = (float*)d_out;

    const size_t MK = (size_t)4 * SEQ * DIM;   // 8M elements
    const size_t WK = (size_t)DIM * DIM;
    unsigned short* wsu = (unsigned short*)d_ws;
    unsigned short* qb  = wsu;
    unsigned short* kb  = qb + MK;
    unsigned short* vb  = kb + MK;
    unsigned short* WqT = vb + MK;
    unsigned short* WkT = WqT + WK;
    unsigned short* WvT = WkT + WK;
    unsigned short* WoT = WvT + WK;
    unsigned short* qp  = WoT + WK;            // bf16 [64][2048][64], scaled log2e/8
    unsigned short* kp  = qp + MK;
    unsigned short* vpT = kp + MK;             // bf16 [64][64][2048]  (transposed V)
    unsigned short* ao  = vpT + MK;

    const int n4 = (int)(MK / 4);
    conv3_f32_bf16<<<dim3((n4 + 255) / 256, 3), 256, 0, stream>>>(q, k, v, qb, kb, vb, n4);
    convT4_f32_bf16<<<dim3(16, 16, 4), 256, 0, stream>>>(Wq, Wk, Wv, Wo, WqT, WkT, WvT, WoT);

    dim3 gg(DIM / 128, (4 * SEQ) / 128);       // (8, 64)
    qk_gemm<<<dim3(8, 64, 2), 256, 0, stream>>>(qb, kb, WqT, WkT, bq, bk, qp, kp);
    v_gemm<<<gg, 256, 0, stream>>>(vb, WvT, bv, vpT);

    attn_mfma<<<dim3(SEQ / 128, 4 * NH), 256, 0, stream>>>(qp, kp, vpT, ao);

    out_gemm<<<gg, 256, 0, stream>>>(ao, WoT, bo, out);
}